// Round 5
// baseline (644.096 us; speedup 1.0000x reference)
//
#include <hip/hip_runtime.h>
#include <math.h>

// 16-qubit statevector, 512 batch. Inter-pass psi FP16 (half2/amp), 128 MiB.
// This round: 2 BATCHES PER BLOCK in all four state passes (grid 4096).
// Rationale: all passes latency-bound (VALU 65%, mem 29%, occ 37%, no pipe
// saturated). Pairing doubles in-wave ILP (2 independent butterfly chains),
// doubles memory-level parallelism, and amortizes ALL address/index algebra
// and gate-register loads across 2 batches. LDS transposes serialize per
// batch (same 32 KB buffer; +3-4 barriers/kernel). Index algebra, swizzles,
// and measurement math bit-identical to the verified sigma scheme.

#define NT 256
#define ACCS 40
#define BSZQ 512

typedef float v2f __attribute__((ext_vector_type(2)));
typedef __fp16 h2t __attribute__((ext_vector_type(2)));

__device__ __forceinline__ v2f mk2(float a, float b){ v2f r; r.x = a; r.y = b; return r; }

__device__ __forceinline__ unsigned int f2h(v2f a){
  h2t h = __builtin_amdgcn_cvt_pkrtz(a.x, a.y);
  return *(unsigned int*)&h;
}
__device__ __forceinline__ v2f h2f(unsigned int u){
  h2t h = *(h2t*)&u;
  return mk2((float)h.x, (float)h.y);
}

// ---- packed fp32 primitives (VOP3P) ----
__device__ __forceinline__ v2f pk_mul(v2f a, v2f b){
  v2f d; asm("v_pk_mul_f32 %0, %1, %2" : "=v"(d) : "v"(a), "v"(b)); return d;
}
__device__ __forceinline__ v2f pk_fma(v2f a, v2f b, v2f c){
  v2f d; asm("v_pk_fma_f32 %0, %1, %2, %3" : "=v"(d) : "v"(a), "v"(b), "v"(c)); return d;
}
__device__ __forceinline__ v2f pk_fma_sw(v2f a, v2f b, v2f c){
  v2f d; asm("v_pk_fma_f32 %0, %1, %2, %3 op_sel:[1,0,0] op_sel_hi:[0,1,1]"
             : "=v"(d) : "v"(a), "v"(b), "v"(c)); return d;
}

struct C2 { float r, i; };
struct G1Q { C2 a, b, c, d; };

__device__ __forceinline__ C2 cmul(C2 x, C2 y){ return C2{ x.r*y.r - x.i*y.i, x.r*y.i + x.i*y.r }; }
__device__ __forceinline__ C2 cadd(C2 x, C2 y){ return C2{ x.r + y.r, x.i + y.i }; }
__device__ __forceinline__ G1Q mkRX(float th){
  float cc = cosf(0.5f*th), ss = sinf(0.5f*th);
  return G1Q{ C2{cc,0.f}, C2{0.f,-ss}, C2{0.f,-ss}, C2{cc,0.f} };
}
__device__ __forceinline__ G1Q mkRY(float th){
  float cc = cosf(0.5f*th), ss = sinf(0.5f*th);
  return G1Q{ C2{cc,0.f}, C2{-ss,0.f}, C2{ss,0.f}, C2{cc,0.f} };
}
__device__ __forceinline__ G1Q gmul(G1Q A, G1Q B){
  return G1Q{ cadd(cmul(A.a,B.a), cmul(A.b,B.c)),
              cadd(cmul(A.a,B.b), cmul(A.b,B.d)),
              cadd(cmul(A.c,B.a), cmul(A.d,B.c)),
              cadd(cmul(A.c,B.b), cmul(A.d,B.d)) };
}

struct PG1Q { v2f aR, aI, bR, bI, cR, cI, dR, dI; };
__device__ __forceinline__ PG1Q loadPG(const float* __restrict__ gt, int i){
  const float4* p = (const float4*)(gt + i*8);
  float4 u = p[0], w = p[1];
  PG1Q g;
  g.aR = mk2(u.x, u.x); g.aI = mk2(-u.y, u.y);
  g.bR = mk2(u.z, u.z); g.bI = mk2(-u.w, u.w);
  g.cR = mk2(w.x, w.x); g.cI = mk2(-w.y, w.y);
  g.dR = mk2(w.z, w.z); g.dI = mk2(-w.w, w.w);
  return g;
}

__device__ __forceinline__ int swzA(int l){ return (l & 0xFF0) | (((l>>4) ^ l) & 15); }
__device__ __forceinline__ int swzB(int l){ return (l & 0xFF0) | (((l>>8) ^ l) & 15); }

template<int M>
__device__ __forceinline__ float swzx(float x){
  return __int_as_float(__builtin_amdgcn_ds_swizzle(__float_as_int(x), (M<<10)|0x1F));
}
__device__ __forceinline__ float wsum(float x){
  x += swzx<1>(x);
  x += swzx<2>(x);
  x += swzx<4>(x);
  x += swzx<8>(x);
  x += swzx<16>(x);
  return __int_as_float(__builtin_amdgcn_readlane(__float_as_int(x), 0)) +
         __int_as_float(__builtin_amdgcn_readlane(__float_as_int(x), 32));
}

__device__ __forceinline__ void greg16p(v2f* v, const PG1Q g, const int q){
  const int bq = 1<<q;
  #pragma unroll
  for (int r=0;r<16;r++){
    if (r & bq) continue;
    v2f a0 = v[r], a1 = v[r|bq];
    v2f t0 = pk_mul(a0, g.aR);
    t0 = pk_fma_sw(a0, g.aI, t0);
    t0 = pk_fma   (a1, g.bR, t0);
    t0 = pk_fma_sw(a1, g.bI, t0);
    v2f t1 = pk_mul(a0, g.cR);
    t1 = pk_fma_sw(a0, g.cI, t1);
    t1 = pk_fma   (a1, g.dR, t1);
    t1 = pk_fma_sw(a1, g.dI, t1);
    v[r] = t0; v[r|bq] = t1;
  }
}
__device__ __forceinline__ void creg16(v2f* v, const int qc, const int qt){
  #pragma unroll
  for (int r=0;r<16;r++){
    if ((r & (1<<qc)) && !(r & (1<<qt))){
      v2f tmp = v[r]; v[r] = v[r|(1<<qt)]; v[r|(1<<qt)] = tmp;
    }
  }
}
__device__ __forceinline__ float xdot16p(const v2f* v, const int m){
  v2f s = pk_mul(v[0], v[m]);
  #pragma unroll
  for (int r=1;r<16;r++) s = pk_fma(v[r], v[r^m], s);
  return s.x + s.y;
}

// ---------------- P0: bake the 14 composed gates (1 thread) ----------------
__global__ void qs_prep(const float* __restrict__ ra, const float* __restrict__ trx,
                        const float* __restrict__ tryv, float* __restrict__ gt){
  if (threadIdx.x != 0) return;
  float trx0 = trx[0];
  G1Q RX0 = mkRX(trx0);
  G1Q g[14];
  g[0]  = gmul(RX0, gmul(mkRY(ra[19]), mkRX(ra[3])));   // p1 alpha q0 (w15)
  g[1]  = mkRX(trx0 + ra[6]);                           // p1 alpha q1
  g[2]  = mkRX(trx0 + ra[9]);                           // p1 alpha q2
  g[3]  = mkRX(trx0 + ra[12]);                          // p1 alpha q3
  g[4]  = mkRX(trx0 + ra[15]);                          // p1 beta q0
  g[5]  = mkRX(trx0 + ra[18]);                          // p1 beta q1
  g[6]  = RX0;                                          // shared
  g[7]  = gmul(RX0, mkRY(ra[4]));                       // p2 A q3 (w4)
  g[8]  = mkRY(ra[1]);                                  // p2 A q2 (w5 RY)
  g[9]  = gmul(RX0, mkRY(ra[7]));                       // p2 B q0 (w3)
  g[10] = gmul(RX0, mkRY(ra[10]));                      // p2 B q1 (w2)
  g[11] = gmul(RX0, mkRY(ra[13]));                      // p2 B q2 (w1)
  g[12] = gmul(RX0, gmul(mkRY(ra[16]), mkRX(ra[0])));   // p2 B q3 (w0)
  g[13] = gmul(mkRX(trx[1]), mkRY(tryv[0]));            // U for p4/p5
  for (int i=0;i<14;i++){
    gt[i*8+0]=g[i].a.r; gt[i*8+1]=g[i].a.i;
    gt[i*8+2]=g[i].b.r; gt[i*8+3]=g[i].b.i;
    gt[i*8+4]=g[i].c.r; gt[i*8+5]=g[i].c.i;
    gt[i*8+6]=g[i].d.r; gt[i*8+7]=g[i].d.i;
  }
}

// ---------------- P1 (L tile, 2 batches/block) ----------------
__global__ __launch_bounds__(NT) void qs_p1(const float* __restrict__ x, const float* __restrict__ gt,
                                            unsigned int* __restrict__ psi, float* __restrict__ acc){
  __shared__ __align__(16) v2f s[4096];
  int bp = blockIdx.x >> 4, t = blockIdx.x & 15;
  int tid = threadIdx.x;
  int b0 = bp*2;
  if (t == 0 && tid < ACCS){ acc[b0*ACCS + tid] = 0.f; acc[(b0+1)*ACCS + tid] = 0.f; }
  v2f v[2][16];
  // phase alpha: regs = bits 0..3, threads = bits 4..11
  {
    float4 f4[2][4];
    #pragma unroll
    for (int j=0;j<2;j++){
      const float4* xb = (const float4*)(x + (size_t)(b0+j)*65536 + t*4096 + tid*16);
      #pragma unroll
      for (int q=0;q<4;q++) f4[j][q] = xb[q];
    }
    #pragma unroll
    for (int j=0;j<2;j++){
      #pragma unroll
      for (int q=0;q<4;q++){
        v[j][4*q+0] = mk2(f4[j][q].x, 0.f);
        v[j][4*q+1] = mk2(f4[j][q].y, 0.f);
        v[j][4*q+2] = mk2(f4[j][q].z, 0.f);
        v[j][4*q+3] = mk2(f4[j][q].w, 0.f);
      }
    }
  }
  {
    PG1Q G0 = loadPG(gt,0), G1 = loadPG(gt,1), G2 = loadPG(gt,2), G3 = loadPG(gt,3);
    #pragma unroll
    for (int j=0;j<2;j++){
      greg16p(v[j], G0, 0);   // w15
      greg16p(v[j], G1, 1);   // w14
      greg16p(v[j], G2, 2);   // w13
      greg16p(v[j], G3, 3);   // w12
    }
  }
  // transition alpha->beta, serialized per batch (WAR barrier between)
  auto WR1 = [&](const v2f* vv){
    #pragma unroll
    for (int k=0;k<16;k++) s[swzA(k | (tid<<4))] = vv[k];
  };
  auto RD1 = [&](v2f* vv){
    #pragma unroll
    for (int r=0;r<16;r++) vv[r] = s[swzA((tid&15) | (r<<4) | ((tid>>4)<<8))];
  };
  WR1(v[0]); __syncthreads(); RD1(v[0]); __syncthreads();
  WR1(v[1]); __syncthreads(); RD1(v[1]);
  // phase beta gates
  {
    PG1Q G4 = loadPG(gt,4), G5 = loadPG(gt,5), G6 = loadPG(gt,6);
    bool c8 = (tid & 16);
    #pragma unroll
    for (int j=0;j<2;j++){
      creg16(v[j], 1, 0);                  // C(w10->w11)
      creg16(v[j], 2, 1);                  // C(w9->w10)
      creg16(v[j], 3, 2);                  // C(w8->w9)
      #pragma unroll
      for (int r=0;r<8;r++){               // C(w7->w8)
        v2f lo = v[j][r], hi = v[j][r|8];
        v[j][r]   = c8 ? hi : lo;
        v[j][r|8] = c8 ? lo : hi;
      }
      greg16p(v[j], G4, 0);   // w11
      greg16p(v[j], G5, 1);   // w10
      greg16p(v[j], G6, 2);   // w9
      greg16p(v[j], G6, 3);   // w8
    }
  }
  #pragma unroll
  for (int j=0;j<2;j++){
    unsigned int* pbL = psi + (size_t)(b0+j)*65536 + t*4096;
    #pragma unroll
    for (int r=0;r<16;r++) pbL[(tid&15) | (r<<4) | ((tid>>4)<<8)] = f2h(v[j][r]);
  }
}

// ---------------- P2 (H tile, 2 batches/block) ----------------
__global__ __launch_bounds__(NT) void qs_p2(unsigned int* __restrict__ psi, const float* __restrict__ gt){
  __shared__ __align__(16) v2f s[4096];
  int bp = blockIdx.x >> 4, t = blockIdx.x & 15;
  int tid = threadIdx.x;
  unsigned int* pb0 = psi + (size_t)(bp*2)*65536;
  unsigned int* pb1 = pb0 + 65536;
  v2f v[2][16];
  // phase A loads (both batches issued together; shared index calc)
  #pragma unroll
  for (int j=0;j<2;j++){
    unsigned int* pb = j ? pb1 : pb0;
    #pragma unroll
    for (int r=0;r<16;r++)
      v[j][r] = h2f(pb[(tid&15) | (t<<4) | (r<<8) | ((tid>>4)<<12)]);
  }
  {
    PG1Q G7 = loadPG(gt,7), G8 = loadPG(gt,8), G6 = loadPG(gt,6);
    #pragma unroll
    for (int j=0;j<2;j++){
      greg16p(v[j], G7, 3);   // w4
      greg16p(v[j], G8, 2);   // w5 (RY part)
      creg16(v[j], 1, 0);     // C(w6->w7)
      creg16(v[j], 2, 1);     // C(w5->w6)
      greg16p(v[j], G6, 2);   // w5
      greg16p(v[j], G6, 1);   // w6
      greg16p(v[j], G6, 0);   // w7
    }
  }
  auto WR2 = [&](const v2f* vv){
    #pragma unroll
    for (int r=0;r<16;r++) s[swzA((tid&15) | (r<<4) | ((tid>>4)<<8))] = vv[r];
  };
  auto RD2 = [&](v2f* vv){
    #pragma unroll
    for (int r=0;r<16;r++) vv[r] = s[swzA((tid&15) | ((tid>>4)<<4) | (r<<8))];
  };
  WR2(v[0]); __syncthreads(); RD2(v[0]); __syncthreads();
  WR2(v[1]); __syncthreads(); RD2(v[1]);
  {
    PG1Q G9 = loadPG(gt,9), G10 = loadPG(gt,10), G11 = loadPG(gt,11), G12 = loadPG(gt,12);
    #pragma unroll
    for (int j=0;j<2;j++){
      greg16p(v[j], G9, 0);    // w3
      greg16p(v[j], G10, 1);   // w2
      greg16p(v[j], G11, 2);   // w1
      greg16p(v[j], G12, 3);   // w0
    }
  }
  #pragma unroll
  for (int j=0;j<2;j++){
    unsigned int* pb = j ? pb1 : pb0;
    #pragma unroll
    for (int r=0;r<16;r++)
      pb[(tid&15) | (t<<4) | ((tid>>4)<<8) | (r<<12)] = f2h(v[j][r]);
  }
}

// ---------------- P4 (H tile on y-frame, 2 batches/block) ----------------
__global__ __launch_bounds__(NT) void qs_p4(unsigned int* __restrict__ psi, const float* __restrict__ gt,
                                            float* __restrict__ acc){
  __shared__ __align__(16) v2f s[4096];
  int bp = blockIdx.x >> 4, t = blockIdx.x & 15;
  int tid = threadIdx.x;
  PG1Q U = loadPG(gt, 13);
  unsigned int* pb0 = psi + (size_t)(bp*2)*65536;
  unsigned int* pb1 = pb0 + 65536;
  v2f v[2][16];
  // LDS mappings
  auto WRA = [&](const v2f* vv){
    #pragma unroll
    for (int k=0;k<16;k++) s[swzB(k | ((tid>>4)<<4) | ((tid&15)<<8))] = vv[k];
  };
  auto RDC = [&](v2f* vv){
    #pragma unroll
    for (int r=0;r<16;r++) vv[r] = s[swzB((tid&15) | ((tid>>4)<<4) | (r<<8))];
  };
  auto WRC = [&](const v2f* vv){
    #pragma unroll
    for (int r=0;r<16;r++) s[swzB((tid&15) | ((tid>>4)<<4) | (r<<8))] = vv[r];
  };
  auto RDB = [&](v2f* vv){
    #pragma unroll
    for (int r=0;r<16;r++) vv[r] = s[swzB((tid&15) | (r<<4) | ((tid>>4)<<8))];
  };
  // ---- phase A: regs y0..3; tid: b0..3 = y12..15, b4..7 = y8..11 ----
  {
    int Y = (tid>>4) | ((tid&15)<<4);          // y8..15
    int XH = Y ^ (Y>>1);                       // x8..15
    int x7 = ((t>>3) ^ Y) & 1;                 // t3 ^ y8
    int runbase = (XH<<8) | (x7<<7) | (((t ^ (t>>1)) & 7) << 4);
    uint4 u4[2][4];
    #pragma unroll
    for (int j=0;j<2;j++){
      const uint4* rp = (const uint4*)((j ? pb1 : pb0) + runbase);
      #pragma unroll
      for (int q=0;q<4;q++) u4[j][q] = rp[q];
    }
    #pragma unroll
    for (int j=0;j<2;j++){
      v2f tmp[16];
      #pragma unroll
      for (int q=0;q<4;q++){
        tmp[4*q+0] = h2f(u4[j][q].x);
        tmp[4*q+1] = h2f(u4[j][q].y);
        tmp[4*q+2] = h2f(u4[j][q].z);
        tmp[4*q+3] = h2f(u4[j][q].w);
      }
      if (t & 1){
        v[j][15]=tmp[0];  v[j][14]=tmp[1];  v[j][12]=tmp[2];  v[j][13]=tmp[3];
        v[j][ 8]=tmp[4];  v[j][ 9]=tmp[5];  v[j][11]=tmp[6];  v[j][10]=tmp[7];
        v[j][ 0]=tmp[8];  v[j][ 1]=tmp[9];  v[j][ 3]=tmp[10]; v[j][ 2]=tmp[11];
        v[j][ 7]=tmp[12]; v[j][ 6]=tmp[13]; v[j][ 4]=tmp[14]; v[j][ 5]=tmp[15];
      } else {
        v[j][ 0]=tmp[0];  v[j][ 1]=tmp[1];  v[j][ 3]=tmp[2];  v[j][ 2]=tmp[3];
        v[j][ 7]=tmp[4];  v[j][ 6]=tmp[5];  v[j][ 4]=tmp[6];  v[j][ 5]=tmp[7];
        v[j][15]=tmp[8];  v[j][14]=tmp[9];  v[j][12]=tmp[10]; v[j][13]=tmp[11];
        v[j][ 8]=tmp[12]; v[j][ 9]=tmp[13]; v[j][11]=tmp[14]; v[j][10]=tmp[15];
      }
      // K = C(w15->w0): ctrl y0 (reg bit0), tgt y15 (lane bit3) -> lane-xor swap
      #pragma unroll
      for (int r=1;r<16;r+=2){
        v[j][r].x = swzx<8>(v[j][r].x);
        v[j][r].y = swzx<8>(v[j][r].y);
      }
      greg16p(v[j], U, 0); greg16p(v[j], U, 1); greg16p(v[j], U, 2); greg16p(v[j], U, 3);
    }
  }
  // A->C transition (serialized per batch)
  WRA(v[0]); __syncthreads(); RDC(v[0]); __syncthreads();
  WRA(v[1]); __syncthreads(); RDC(v[1]);
  float Xa[2], Xb[2], Xc[2], Xd[2];
  // ---- phase C: regs y12..15; tid: b0..3 = y0..3, b4..7 = y8..11 ----
  #pragma unroll
  for (int j=0;j<2;j++){
    greg16p(v[j], U, 0); greg16p(v[j], U, 1); greg16p(v[j], U, 2); greg16p(v[j], U, 3);
    creg16(v[j], 3, 2);  // chain1 C(w0->w1)
    creg16(v[j], 2, 1);  // C(w1->w2)
    creg16(v[j], 1, 0);  // C(w2->w3)
    Xa[j] = xdot16p(v[j], 8);   // X_w0 (y15)
    Xb[j] = xdot16p(v[j], 4);   // X_w1 (y14)
    Xc[j] = xdot16p(v[j], 2);   // X_w2 (y13)
    v2f XdP = mk2(0.f, 0.f);    // <X_w0 X_w15>
    #pragma unroll
    for (int r=0;r<16;r++)
      XdP = pk_fma(v[j][r], mk2(swzx<1>(v[j][r^8].x), swzx<1>(v[j][r^8].y)), XdP);
    Xd[j] = XdP.x + XdP.y;
  }
  // C->B transition (leading bar: all C-reads of batch1 complete before overwrite)
  __syncthreads();
  WRC(v[0]); __syncthreads(); RDB(v[0]); __syncthreads();
  WRC(v[1]); __syncthreads(); RDB(v[1]);
  float Xe[2], Xf[2], Xg[2], Xh[2];
  // ---- phase B: regs y8..11; tid: b0..3 = y0..3, b4..7 = y12..15 ----
  {
    bool c12 = (tid & 16);
    int Bs = (tid&15) | (t<<4) | ((tid>>4)<<12);
    int Cs = Bs ^ (Bs>>1);
    #pragma unroll
    for (int j=0;j<2;j++){
      greg16p(v[j], U, 0); greg16p(v[j], U, 1); greg16p(v[j], U, 2); greg16p(v[j], U, 3);
      #pragma unroll
      for (int r=0;r<8;r++){             // C(w3->w4)
        v2f lo = v[j][r], hi = v[j][r|8];
        v[j][r]   = c12 ? hi : lo;
        v[j][r|8] = c12 ? lo : hi;
      }
      creg16(v[j], 3, 2);  // C(w4->w5)
      creg16(v[j], 2, 1);  // C(w5->w6)
      creg16(v[j], 1, 0);  // C(w6->w7)
      v2f XeP = mk2(0.f, 0.f);   // X_w3 (y12 = lane bit4)
      #pragma unroll
      for (int r=0;r<16;r++)
        XeP = pk_fma(v[j][r], mk2(swzx<16>(v[j][r].x), swzx<16>(v[j][r].y)), XeP);
      Xe[j] = XeP.x + XeP.y;
      Xf[j] = xdot16p(v[j], 8);   // X_w4
      Xg[j] = xdot16p(v[j], 4);   // X_w5
      Xh[j] = xdot16p(v[j], 2);   // X_w6
      unsigned int* pb = j ? pb1 : pb0;
      #pragma unroll
      for (int r=0;r<16;r++)
        pb[Cs ^ ((r<<8) ^ (r<<7))] = f2h(v[j][r]);
    }
  }
  #pragma unroll
  for (int j=0;j<2;j++){
    float vals[8] = {Xa[j], Xb[j], Xc[j], Xe[j], Xf[j], Xg[j], Xh[j], Xd[j]};
    #pragma unroll
    for (int i=0;i<8;i++) vals[i] = wsum(vals[i]);
    if ((tid & 63) == 0){
      float* A = acc + (bp*2 + j)*ACCS;
      #pragma unroll
      for (int i=0;i<7;i++) atomicAdd(A+25+i, vals[i]);
      atomicAdd(A+32, vals[7]);
    }
  }
}

// ---------------- P5 (L tile, read-only, no LDS, 2 batches/block) ----------------
// Gathers for both batches issued together (2x MLP); measures serialized per
// batch to bound register pressure.
__global__ __launch_bounds__(NT) void qs_p5(const unsigned int* __restrict__ psi, const float* __restrict__ gt,
                                            float* __restrict__ acc){
  int bp = blockIdx.x >> 4, t = blockIdx.x & 15;
  int tid = threadIdx.x;
  PG1Q U = loadPG(gt, 13);
  const unsigned int* pb0 = psi + (size_t)(bp*2)*65536;
  const unsigned int* pb1 = pb0 + 65536;
  v2f v[2][16];
  int Bv = (t<<12) | ((tid>>4)<<8) | (tid&15);
  int Cg = Bv ^ (Bv>>1);
  #pragma unroll
  for (int j=0;j<2;j++){
    const unsigned int* pb = j ? pb1 : pb0;
    #pragma unroll
    for (int r=0;r<16;r++)
      v[j][r] = h2f(pb[Cg ^ ((r<<4) ^ (r<<3))]);
  }
  #pragma unroll
  for (int j=0;j<2;j++){
    greg16p(v[j], U, 0); greg16p(v[j], U, 1); greg16p(v[j], U, 2); greg16p(v[j], U, 3);
  }
  #pragma unroll
  for (int j=0;j<2;j++){
    v2f z2 = mk2(0.f, 0.f);
    v2f totP=z2, S4P=z2, S5P=z2, S6P=z2, S7P=z2;
    #pragma unroll
    for (int r=0;r<16;r++){
      v2f sq = pk_mul(v[j][r], v[j][r]);
      totP = totP + sq;
      if (__popc(r)&1)    S4P = S4P + sq;
      if (__popc(r>>1)&1) S5P = S5P + sq;
      if (__popc(r>>2)&1) S6P = S6P + sq;
      if (__popc(r>>3)&1) S7P = S7P + sq;
    }
    float totA = totP.x + totP.y;
    float S4l = S4P.x + S4P.y, S5l = S5P.x + S5P.y;
    float S6l = S6P.x + S6P.y, S7l = S7P.x + S7P.y;
    float S4h = totA - S4l;
    float S0 = (__popc(tid & 0x1F)&1) ? S4h : S4l;
    float S1 = (__popc(tid & 0x1E)&1) ? S4h : S4l;
    float S2 = (__popc(tid & 0x1C)&1) ? S4h : S4l;
    float S3 = (__popc(tid & 0x18)&1) ? S4h : S4l;
    bool u8 = (tid & 16);
    float S4 = u8 ? S4h : S4l;
    float S5 = u8 ? totA - S5l : S5l;
    float S6 = u8 ? totA - S6l : S6l;
    float S7 = u8 ? totA - S7l : S7l;
    float S8 = u8 ? totA : 0.f;
    float K9  = (tid & 32) ? totA : 0.f;
    float K10 = (tid & 64) ? totA : 0.f;
    float K11 = (tid & 128)? totA : 0.f;
    float X45 = xdot16p(v[j],3), X56 = xdot16p(v[j],6), X67 = xdot16p(v[j],12);
    v2f X01P=z2, X12P=z2, X23P=z2, X34P=z2, X78P=z2;
    #pragma unroll
    for (int r=0;r<16;r++){
      float vx = v[j][r].x, vy = v[j][r].y;
      X01P = pk_fma(v[j][r], mk2(swzx<3>(vx),  swzx<3>(vy)),  X01P);
      X12P = pk_fma(v[j][r], mk2(swzx<6>(vx),  swzx<6>(vy)),  X12P);
      X23P = pk_fma(v[j][r], mk2(swzx<12>(vx), swzx<12>(vy)), X23P);
      X34P = pk_fma(v[j][r], mk2(swzx<8>(v[j][r^1].x), swzx<8>(v[j][r^1].y)), X34P);
      X78P = pk_fma(v[j][r], mk2(swzx<16>(v[j][r^8].x), swzx<16>(v[j][r^8].y)), X78P);
    }
    float X01 = X01P.x + X01P.y, X12 = X12P.x + X12P.y, X23 = X23P.x + X23P.y;
    float X34 = X34P.x + X34P.y, X78 = X78P.x + X78P.y;
    float vals[21] = {totA, S0,S1,S2,S3,S4,S5,S6,S7,S8, K9,K10,K11,
                      X01,X12,X23,X34,X45,X56,X67,X78};
    #pragma unroll
    for (int i=0;i<21;i++) vals[i] = wsum(vals[i]);
    if ((tid & 63) == 0){
      float* A = acc + (bp*2 + j)*ACCS;
      atomicAdd(A+0, vals[0]);
      #pragma unroll
      for (int p=0;p<12;p++) atomicAdd(A+1+p, vals[1+p]);
      if (t&1) atomicAdd(A+13, vals[0]);
      if (t&2) atomicAdd(A+14, vals[0]);
      if (t&4) atomicAdd(A+15, vals[0]);
      float zz = vals[0] - 2.f*vals[1];
      if (t&8) zz = -zz;
      atomicAdd(A+16, zz);
      #pragma unroll
      for (int jj=0;jj<8;jj++) atomicAdd(A+17+jj, vals[13+jj]);
    }
  }
}

// ---------------- Tail (unchanged, verified) ----------------
__global__ __launch_bounds__(256) void qs_tail(const float* __restrict__ acc, const float* __restrict__ tryv,
    const float* __restrict__ w1, const float* __restrict__ b1,
    const float* __restrict__ w2, const float* __restrict__ b2,
    const float* __restrict__ g1, const float* __restrict__ be1,
    const float* __restrict__ g2, const float* __restrict__ be2,
    const float* __restrict__ wh, const float* __restrict__ bh,
    float* __restrict__ out){
  int b = blockIdx.x * 256 + threadIdx.x;
  if (b >= BSZQ) return;
  const float* A = acc + b*ACCS;
  float tot = A[0];
  float inv = 1.f / tot;
  float Z[16], X[16];
  Z[0] = A[16] * inv;
  Z[1] = 1.f - 2.f*A[15]*inv;
  Z[2] = 1.f - 2.f*A[14]*inv;
  Z[3] = 1.f - 2.f*A[13]*inv;
  #pragma unroll
  for (int w=4; w<15; w++) Z[w] = 1.f - 2.f*A[1 + (15-w)]*inv;
  Z[15] = 1.f - 2.f*A[1]*inv;
  #pragma unroll
  for (int w=0; w<7; w++) X[w] = A[25+w]*inv;
  #pragma unroll
  for (int w=7; w<15; w++) X[w] = A[16 + (15-w)]*inv;
  X[15] = A[32]*inv;
  float th = tryv[1];
  float ct = cosf(th), st = sinf(th);
  float M4[16];
  #pragma unroll
  for (int w=0; w<16; w++) M4[w] = ct*Z[w] - st*X[w];
  float mu = 0.f;
  #pragma unroll
  for (int w=0; w<16; w++) mu += Z[w];
  mu *= (1.f/16.f);
  float var = 0.f;
  #pragma unroll
  for (int w=0; w<16; w++){ float d = Z[w]-mu; var += d*d; }
  var *= (1.f/16.f);
  float rs = rsqrtf(var + 1e-5f);
  float xln[16];
  #pragma unroll
  for (int w=0; w<16; w++) xln[w] = (Z[w]-mu)*rs*g1[16+w] + be1[16+w];
  float h[64];
  for (int j=0;j<64;j++){
    float sacc = b1[64 + j];
    #pragma unroll
    for (int w=0; w<16; w++) sacc += M4[w] * w1[1024 + j*16 + w];
    h[j] = fmaxf(sacc, 0.f);
  }
  float y[16];
  for (int w=0; w<16; w++){
    float sacc = b2[16 + w];
    #pragma unroll
    for (int j=0;j<64;j++) sacc += h[j] * w2[1024 + w*64 + j];
    y[w] = xln[w] + sacc;
  }
  mu = 0.f;
  #pragma unroll
  for (int w=0; w<16; w++) mu += y[w];
  mu *= (1.f/16.f);
  var = 0.f;
  #pragma unroll
  for (int w=0; w<16; w++){ float d = y[w]-mu; var += d*d; }
  var *= (1.f/16.f);
  rs = rsqrtf(var + 1e-5f);
  float o = bh[0];
  #pragma unroll
  for (int w=0; w<16; w++) o += ((y[w]-mu)*rs*g2[16+w] + be2[16+w]) * wh[w];
  out[b] = o;
}

extern "C" void kernel_launch(void* const* d_in, const int* in_sizes, int n_in,
                              void* d_out, int out_size, void* d_ws, size_t ws_size,
                              hipStream_t stream) {
  const float* states = (const float*)d_in[0];
  const float* ra     = (const float*)d_in[1];
  const float* trx    = (const float*)d_in[2];
  const float* tryv   = (const float*)d_in[3];
  const float* w1     = (const float*)d_in[4];
  const float* b1     = (const float*)d_in[5];
  const float* w2     = (const float*)d_in[6];
  const float* b2     = (const float*)d_in[7];
  const float* g1     = (const float*)d_in[8];
  const float* be1    = (const float*)d_in[9];
  const float* g2     = (const float*)d_in[10];
  const float* be2    = (const float*)d_in[11];
  const float* wh     = (const float*)d_in[12];
  const float* bh     = (const float*)d_in[13];
  float* out = (float*)d_out;

  unsigned int* psi = (unsigned int*)d_ws;                                 // 128 MiB (fp16 amps)
  float* acc  = (float*)((char*)d_ws + (size_t)BSZQ*65536*sizeof(float2)); // keep old offset (512 x 40)
  float* gt = out;  // gate table in d_out scratch; qs_tail overwrites it all

  dim3 g2x((BSZQ/2)*16);
  qs_prep<<<1, 64, 0, stream>>>(ra, trx, tryv, gt);
  qs_p1<<<g2x, NT, 0, stream>>>(states, gt, psi, acc);
  qs_p2<<<g2x, NT, 0, stream>>>(psi, gt);
  qs_p4<<<g2x, NT, 0, stream>>>(psi, gt, acc);
  qs_p5<<<g2x, NT, 0, stream>>>(psi, gt, acc);
  qs_tail<<<2, 256, 0, stream>>>(acc, tryv, w1, b1, w2, b2, g1, be1, g2, be2, wh, bh, out);
}

// Round 6
// 538.608 us; speedup vs baseline: 1.1959x; 1.1959x over previous
//
#include <hip/hip_runtime.h>
#include <math.h>

// 16-qubit statevector, 512 batch. Inter-pass psi FP16 (half2/amp), 128 MiB.
// This round: REVERT round-5 pairing (compiler serialized the two batches:
// VGPR 52 proves both chains were never co-live). Back to verified round-4
// structure, plus BARRIER ELIMINATION: the p1 and p4(A->C) LDS transposes
// exchange data only within 16-consecutive-thread groups (reader (a,b) reg r
// <- writer (r,b) reg a, partners share tid>>4) => fully intra-wave. DS ops
// from one wave execute in order, so these need only a compile-time fence,
// not __syncthreads. p4's RDC->WRC overwrite touches only the thread's own
// region {a,b,*} => no barrier. Inter-wave transposes (p2, p4 C->B) keep
// their single barrier. p1: 1->0 barriers; p4: 4->1. Math bit-identical.

#define NT 256
#define ACCS 40
#define BSZQ 512

typedef float v2f __attribute__((ext_vector_type(2)));
typedef __fp16 h2t __attribute__((ext_vector_type(2)));

__device__ __forceinline__ v2f mk2(float a, float b){ v2f r; r.x = a; r.y = b; return r; }

// Compile-time ordering fence for intra-wave LDS exchange (no HW cost).
__device__ __forceinline__ void wave_fence(){
  asm volatile("" ::: "memory");
  __builtin_amdgcn_wave_barrier();
  asm volatile("" ::: "memory");
}

__device__ __forceinline__ unsigned int f2h(v2f a){
  h2t h = __builtin_amdgcn_cvt_pkrtz(a.x, a.y);
  return *(unsigned int*)&h;
}
__device__ __forceinline__ v2f h2f(unsigned int u){
  h2t h = *(h2t*)&u;
  return mk2((float)h.x, (float)h.y);
}

// ---- packed fp32 primitives (VOP3P) ----
__device__ __forceinline__ v2f pk_mul(v2f a, v2f b){
  v2f d; asm("v_pk_mul_f32 %0, %1, %2" : "=v"(d) : "v"(a), "v"(b)); return d;
}
__device__ __forceinline__ v2f pk_fma(v2f a, v2f b, v2f c){
  v2f d; asm("v_pk_fma_f32 %0, %1, %2, %3" : "=v"(d) : "v"(a), "v"(b), "v"(c)); return d;
}
__device__ __forceinline__ v2f pk_fma_sw(v2f a, v2f b, v2f c){
  v2f d; asm("v_pk_fma_f32 %0, %1, %2, %3 op_sel:[1,0,0] op_sel_hi:[0,1,1]"
             : "=v"(d) : "v"(a), "v"(b), "v"(c)); return d;
}

struct C2 { float r, i; };
struct G1Q { C2 a, b, c, d; };

__device__ __forceinline__ C2 cmul(C2 x, C2 y){ return C2{ x.r*y.r - x.i*y.i, x.r*y.i + x.i*y.r }; }
__device__ __forceinline__ C2 cadd(C2 x, C2 y){ return C2{ x.r + y.r, x.i + y.i }; }
__device__ __forceinline__ G1Q mkRX(float th){
  float cc = cosf(0.5f*th), ss = sinf(0.5f*th);
  return G1Q{ C2{cc,0.f}, C2{0.f,-ss}, C2{0.f,-ss}, C2{cc,0.f} };
}
__device__ __forceinline__ G1Q mkRY(float th){
  float cc = cosf(0.5f*th), ss = sinf(0.5f*th);
  return G1Q{ C2{cc,0.f}, C2{-ss,0.f}, C2{ss,0.f}, C2{cc,0.f} };
}
__device__ __forceinline__ G1Q gmul(G1Q A, G1Q B){
  return G1Q{ cadd(cmul(A.a,B.a), cmul(A.b,B.c)),
              cadd(cmul(A.a,B.b), cmul(A.b,B.d)),
              cadd(cmul(A.c,B.a), cmul(A.d,B.c)),
              cadd(cmul(A.c,B.b), cmul(A.d,B.d)) };
}

struct PG1Q { v2f aR, aI, bR, bI, cR, cI, dR, dI; };
__device__ __forceinline__ PG1Q loadPG(const float* __restrict__ gt, int i){
  const float4* p = (const float4*)(gt + i*8);
  float4 u = p[0], w = p[1];
  PG1Q g;
  g.aR = mk2(u.x, u.x); g.aI = mk2(-u.y, u.y);
  g.bR = mk2(u.z, u.z); g.bI = mk2(-u.w, u.w);
  g.cR = mk2(w.x, w.x); g.cI = mk2(-w.y, w.y);
  g.dR = mk2(w.z, w.z); g.dI = mk2(-w.w, w.w);
  return g;
}

__device__ __forceinline__ int swzA(int l){ return (l & 0xFF0) | (((l>>4) ^ l) & 15); }
__device__ __forceinline__ int swzB(int l){ return (l & 0xFF0) | (((l>>8) ^ l) & 15); }

template<int M>
__device__ __forceinline__ float swzx(float x){
  return __int_as_float(__builtin_amdgcn_ds_swizzle(__float_as_int(x), (M<<10)|0x1F));
}
__device__ __forceinline__ float wsum(float x){
  x += swzx<1>(x);
  x += swzx<2>(x);
  x += swzx<4>(x);
  x += swzx<8>(x);
  x += swzx<16>(x);
  return __int_as_float(__builtin_amdgcn_readlane(__float_as_int(x), 0)) +
         __int_as_float(__builtin_amdgcn_readlane(__float_as_int(x), 32));
}

__device__ __forceinline__ void greg16p(v2f* v, const PG1Q g, const int q){
  const int bq = 1<<q;
  #pragma unroll
  for (int r=0;r<16;r++){
    if (r & bq) continue;
    v2f a0 = v[r], a1 = v[r|bq];
    v2f t0 = pk_mul(a0, g.aR);
    t0 = pk_fma_sw(a0, g.aI, t0);
    t0 = pk_fma   (a1, g.bR, t0);
    t0 = pk_fma_sw(a1, g.bI, t0);
    v2f t1 = pk_mul(a0, g.cR);
    t1 = pk_fma_sw(a0, g.cI, t1);
    t1 = pk_fma   (a1, g.dR, t1);
    t1 = pk_fma_sw(a1, g.dI, t1);
    v[r] = t0; v[r|bq] = t1;
  }
}
__device__ __forceinline__ void creg16(v2f* v, const int qc, const int qt){
  #pragma unroll
  for (int r=0;r<16;r++){
    if ((r & (1<<qc)) && !(r & (1<<qt))){
      v2f tmp = v[r]; v[r] = v[r|(1<<qt)]; v[r|(1<<qt)] = tmp;
    }
  }
}
__device__ __forceinline__ float xdot16p(const v2f* v, const int m){
  v2f s = pk_mul(v[0], v[m]);
  #pragma unroll
  for (int r=1;r<16;r++) s = pk_fma(v[r], v[r^m], s);
  return s.x + s.y;
}

// ---------------- P0: bake the 14 composed gates (1 thread) ----------------
__global__ void qs_prep(const float* __restrict__ ra, const float* __restrict__ trx,
                        const float* __restrict__ tryv, float* __restrict__ gt){
  if (threadIdx.x != 0) return;
  float trx0 = trx[0];
  G1Q RX0 = mkRX(trx0);
  G1Q g[14];
  g[0]  = gmul(RX0, gmul(mkRY(ra[19]), mkRX(ra[3])));   // p1 alpha q0 (w15)
  g[1]  = mkRX(trx0 + ra[6]);                           // p1 alpha q1
  g[2]  = mkRX(trx0 + ra[9]);                           // p1 alpha q2
  g[3]  = mkRX(trx0 + ra[12]);                          // p1 alpha q3
  g[4]  = mkRX(trx0 + ra[15]);                          // p1 beta q0
  g[5]  = mkRX(trx0 + ra[18]);                          // p1 beta q1
  g[6]  = RX0;                                          // shared
  g[7]  = gmul(RX0, mkRY(ra[4]));                       // p2 A q3 (w4)
  g[8]  = mkRY(ra[1]);                                  // p2 A q2 (w5 RY)
  g[9]  = gmul(RX0, mkRY(ra[7]));                       // p2 B q0 (w3)
  g[10] = gmul(RX0, mkRY(ra[10]));                      // p2 B q1 (w2)
  g[11] = gmul(RX0, mkRY(ra[13]));                      // p2 B q2 (w1)
  g[12] = gmul(RX0, gmul(mkRY(ra[16]), mkRX(ra[0])));   // p2 B q3 (w0)
  g[13] = gmul(mkRX(trx[1]), mkRY(tryv[0]));            // U for p4/p5
  for (int i=0;i<14;i++){
    gt[i*8+0]=g[i].a.r; gt[i*8+1]=g[i].a.i;
    gt[i*8+2]=g[i].b.r; gt[i*8+3]=g[i].b.i;
    gt[i*8+4]=g[i].c.r; gt[i*8+5]=g[i].c.i;
    gt[i*8+6]=g[i].d.r; gt[i*8+7]=g[i].d.i;
  }
}

// ---------------- P1 (L tile): input->complex, random-layer L gates + RX0 ----------------
// LDS transpose is intra-wave (partners share tid>>4) -> NO __syncthreads.
__global__ __launch_bounds__(NT) void qs_p1(const float* __restrict__ x, const float* __restrict__ gt,
                                            unsigned int* __restrict__ psi, float* __restrict__ acc){
  __shared__ __align__(16) v2f s[4096];
  int b = blockIdx.x >> 4, t = blockIdx.x & 15;
  int tid = threadIdx.x;
  if (t == 0 && tid < ACCS) acc[b*ACCS + tid] = 0.f;
  v2f v[16];
  // phase alpha: regs = bits 0..3, threads = bits 4..11
  const float4* xb = (const float4*)(x + (size_t)b*65536 + t*4096 + tid*16);
  #pragma unroll
  for (int q=0;q<4;q++){
    float4 f = xb[q];
    v[4*q+0] = mk2(f.x, 0.f);
    v[4*q+1] = mk2(f.y, 0.f);
    v[4*q+2] = mk2(f.z, 0.f);
    v[4*q+3] = mk2(f.w, 0.f);
  }
  greg16p(v, loadPG(gt,0), 0);   // w15
  greg16p(v, loadPG(gt,1), 1);   // w14
  greg16p(v, loadPG(gt,2), 2);   // w13
  greg16p(v, loadPG(gt,3), 3);   // w12
  #pragma unroll
  for (int j=0;j<16;j++) s[swzA(j | (tid<<4))] = v[j];
  wave_fence();
  // phase beta: regs = bits 4..7; tid: b0..3 = bits 0..3, b4..7 = bits 8..11
  #pragma unroll
  for (int r=0;r<16;r++) v[r] = s[swzA((tid&15) | (r<<4) | ((tid>>4)<<8))];
  creg16(v, 1, 0);                       // C(w10->w11)
  creg16(v, 2, 1);                       // C(w9->w10)
  creg16(v, 3, 2);                       // C(w8->w9)
  {                                      // C(w7->w8): ctrl bit8 = tid bit4, tgt bit7 = r3
    bool c8 = (tid & 16);
    #pragma unroll
    for (int r=0;r<8;r++){
      v2f lo = v[r], hi = v[r|8];
      v[r]   = c8 ? hi : lo;
      v[r|8] = c8 ? lo : hi;
    }
  }
  greg16p(v, loadPG(gt,4), 0);   // w11
  greg16p(v, loadPG(gt,5), 1);   // w10
  PG1Q PG6 = loadPG(gt,6);
  greg16p(v, PG6, 2);            // w9
  greg16p(v, PG6, 3);            // w8
  unsigned int* pbL = psi + (size_t)b*65536 + t*4096;
  #pragma unroll
  for (int r=0;r<16;r++) pbL[(tid&15) | (r<<4) | ((tid>>4)<<8)] = f2h(v[r]);
}

// ---------------- P2 (H tile): random-layer H gates + RX0 on wires 0..7 ----------------
// Transpose partners vary tid>>4 (inter-wave) -> keep the single barrier.
__global__ __launch_bounds__(NT) void qs_p2(unsigned int* __restrict__ psi, const float* __restrict__ gt){
  __shared__ __align__(16) v2f s[4096];
  int b = blockIdx.x >> 4, t = blockIdx.x & 15;
  int tid = threadIdx.x;
  v2f v[16];
  unsigned int* pb = psi + (size_t)b*65536;
  // phase A: regs = g8..11; tid: b0..3 = g0..3, b4..7 = g12..15
  #pragma unroll
  for (int r=0;r<16;r++)
    v[r] = h2f(pb[(tid&15) | (t<<4) | (r<<8) | ((tid>>4)<<12)]);
  greg16p(v, loadPG(gt,7), 3);   // w4
  greg16p(v, loadPG(gt,8), 2);   // w5 (RY part)
  creg16(v, 1, 0);               // C(w6->w7)
  creg16(v, 2, 1);               // C(w5->w6)
  PG1Q PG6 = loadPG(gt,6);
  greg16p(v, PG6, 2);            // w5
  greg16p(v, PG6, 1);            // w6
  greg16p(v, PG6, 0);            // w7
  #pragma unroll
  for (int r=0;r<16;r++) s[swzA((tid&15) | (r<<4) | ((tid>>4)<<8))] = v[r];
  __syncthreads();
  // phase B: regs = g12..15; tid: b0..3 = g0..3, b4..7 = g8..11
  #pragma unroll
  for (int r=0;r<16;r++) v[r] = s[swzA((tid&15) | ((tid>>4)<<4) | (r<<8))];
  greg16p(v, loadPG(gt,9), 0);    // w3
  greg16p(v, loadPG(gt,10), 1);   // w2
  greg16p(v, loadPG(gt,11), 2);   // w1
  greg16p(v, loadPG(gt,12), 3);   // w0
  #pragma unroll
  for (int r=0;r<16;r++)
    pb[(tid&15) | (t<<4) | ((tid>>4)<<8) | (r<<12)] = f2h(v[r]);
}

// ---------------- P4 (H tile on y-frame, T folded into load/store addr) ----------------
// Phases A (y0..3) -> C (y12..15) -> B (y8..11). A->C transpose intra-wave
// (no barrier); RDC->WRC overwrites only the thread's own region (no barrier);
// C->B transpose inter-wave (1 barrier).
__global__ __launch_bounds__(NT) void qs_p4(unsigned int* __restrict__ psi, const float* __restrict__ gt,
                                            float* __restrict__ acc){
  __shared__ __align__(16) v2f s[4096];
  int b = blockIdx.x >> 4, t = blockIdx.x & 15;
  int tid = threadIdx.x;
  PG1Q U = loadPG(gt, 13);
  unsigned int* pb = psi + (size_t)b*65536;
  v2f v[16];
  // ---- phase A: regs y0..3; tid: b0..3 = y12..15, b4..7 = y8..11 ----
  {
    int Y = (tid>>4) | ((tid&15)<<4);          // y8..15
    int XH = Y ^ (Y>>1);                       // x8..15
    int x7 = ((t>>3) ^ Y) & 1;                 // t3 ^ y8
    int runbase = (XH<<8) | (x7<<7) | (((t ^ (t>>1)) & 7) << 4);
    const uint4* rp = (const uint4*)(pb + runbase);
    v2f tmp[16];
    #pragma unroll
    for (int q=0;q<4;q++){
      uint4 u = rp[q];
      tmp[4*q+0] = h2f(u.x);
      tmp[4*q+1] = h2f(u.y);
      tmp[4*q+2] = h2f(u.z);
      tmp[4*q+3] = h2f(u.w);
    }
    // v[j] = tmp[alpha], j bitk = parity(alpha>>k) (^15 if t0)
    if (t & 1){
      v[15]=tmp[0];  v[14]=tmp[1];  v[12]=tmp[2];  v[13]=tmp[3];
      v[ 8]=tmp[4];  v[ 9]=tmp[5];  v[11]=tmp[6];  v[10]=tmp[7];
      v[ 0]=tmp[8];  v[ 1]=tmp[9];  v[ 3]=tmp[10]; v[ 2]=tmp[11];
      v[ 7]=tmp[12]; v[ 6]=tmp[13]; v[ 4]=tmp[14]; v[ 5]=tmp[15];
    } else {
      v[ 0]=tmp[0];  v[ 1]=tmp[1];  v[ 3]=tmp[2];  v[ 2]=tmp[3];
      v[ 7]=tmp[4];  v[ 6]=tmp[5];  v[ 4]=tmp[6];  v[ 5]=tmp[7];
      v[15]=tmp[8];  v[14]=tmp[9];  v[12]=tmp[10]; v[13]=tmp[11];
      v[ 8]=tmp[12]; v[ 9]=tmp[13]; v[11]=tmp[14]; v[10]=tmp[15];
    }
    // K = C(w15->w0): ctrl y0 (reg bit0), tgt y15 (lane bit3) -> lane-xor swap
    #pragma unroll
    for (int r=1;r<16;r+=2){
      v[r].x = swzx<8>(v[r].x);
      v[r].y = swzx<8>(v[r].y);
    }
    greg16p(v, U, 0); greg16p(v, U, 1); greg16p(v, U, 2); greg16p(v, U, 3); // w15,w14,w13,w12
    #pragma unroll
    for (int j=0;j<16;j++)
      s[swzB(j | ((tid>>4)<<4) | ((tid&15)<<8))] = v[j];
  }
  wave_fence();   // A->C transpose is intra-wave (partners share tid>>4)
  float Xa, Xb, Xc, Xd;
  // ---- phase C: regs y12..15; tid: b0..3 = y0..3, b4..7 = y8..11 ----
  {
    #pragma unroll
    for (int r=0;r<16;r++)
      v[r] = s[swzB((tid&15) | ((tid>>4)<<4) | (r<<8))];
    greg16p(v, U, 0); greg16p(v, U, 1); greg16p(v, U, 2); greg16p(v, U, 3); // w3,w2,w1,w0
    creg16(v, 3, 2);  // chain1 C(w0->w1)
    creg16(v, 2, 1);  // C(w1->w2)
    creg16(v, 1, 0);  // C(w2->w3)
    Xa = xdot16p(v, 8);   // X_w0 (y15)
    Xb = xdot16p(v, 4);   // X_w1 (y14)
    Xc = xdot16p(v, 2);   // X_w2 (y13)
    v2f XdP = mk2(0.f, 0.f);  // <X_w0 X_w15> = y15 (reg) x y0 (lane bit0)
    #pragma unroll
    for (int r=0;r<16;r++)
      XdP = pk_fma(v[r], mk2(swzx<1>(v[r^8].x), swzx<1>(v[r^8].y)), XdP);
    Xd = XdP.x + XdP.y;
    wave_fence();   // RDC -> WRC: each thread overwrites only its own region {a,b,*}
    #pragma unroll
    for (int r=0;r<16;r++)
      s[swzB((tid&15) | ((tid>>4)<<4) | (r<<8))] = v[r];
  }
  __syncthreads();  // C->B transpose is inter-wave: the one required barrier
  // ---- phase B: regs y8..11; tid: b0..3 = y0..3, b4..7 = y12..15 ----
  float Xe, Xf, Xg, Xh;
  {
    #pragma unroll
    for (int r=0;r<16;r++)
      v[r] = s[swzB((tid&15) | (r<<4) | ((tid>>4)<<8))];
    greg16p(v, U, 0); greg16p(v, U, 1); greg16p(v, U, 2); greg16p(v, U, 3); // w7,w6,w5,w4
    {                                  // C(w3->w4): ctrl y12 = tid bit4, tgt y11 = r3
      bool c12 = (tid & 16);
      #pragma unroll
      for (int r=0;r<8;r++){
        v2f lo = v[r], hi = v[r|8];
        v[r]   = c12 ? hi : lo;
        v[r|8] = c12 ? lo : hi;
      }
    }
    creg16(v, 3, 2);  // C(w4->w5)
    creg16(v, 2, 1);  // C(w5->w6)
    creg16(v, 1, 0);  // C(w6->w7)
    v2f XeP = mk2(0.f, 0.f);   // X_w3 (y12 = lane bit4)
    #pragma unroll
    for (int r=0;r<16;r++)
      XeP = pk_fma(v[r], mk2(swzx<16>(v[r].x), swzx<16>(v[r].y)), XeP);
    Xe = XeP.x + XeP.y;
    Xf = xdot16p(v, 8);   // X_w4
    Xg = xdot16p(v, 4);   // X_w5
    Xh = xdot16p(v, 2);   // X_w6
    // store, T folded: g(base|r<<8) = g(base) ^ ((r<<8)^(r<<7))
    int Bs = (tid&15) | (t<<4) | ((tid>>4)<<12);
    int Cs = Bs ^ (Bs>>1);
    #pragma unroll
    for (int r=0;r<16;r++)
      pb[Cs ^ ((r<<8) ^ (r<<7))] = f2h(v[r]);
  }
  float vals[8] = {Xa, Xb, Xc, Xe, Xf, Xg, Xh, Xd};
  #pragma unroll
  for (int i=0;i<8;i++) vals[i] = wsum(vals[i]);
  if ((tid & 63) == 0){
    float* A = acc + b*ACCS;
    #pragma unroll
    for (int i=0;i<7;i++) atomicAdd(A+25+i, vals[i]);
    atomicAdd(A+32, vals[7]);
  }
}

// ---------------- P5 (L tile, read-only, single-phase, no LDS) ----------------
__global__ __launch_bounds__(NT) void qs_p5(const unsigned int* __restrict__ psi, const float* __restrict__ gt,
                                            float* __restrict__ acc){
  int b = blockIdx.x >> 4, t = blockIdx.x & 15;
  int tid = threadIdx.x;
  PG1Q U = loadPG(gt, 13);
  const unsigned int* pb = psi + (size_t)b*65536;
  v2f v[16];
  // T-unfold gather, strength-reduced: addr(r) = g(Bv) ^ ((r<<4)^(r<<3))
  int Bv = (t<<12) | ((tid>>4)<<8) | (tid&15);
  int Cg = Bv ^ (Bv>>1);
  #pragma unroll
  for (int r=0;r<16;r++)
    v[r] = h2f(pb[Cg ^ ((r<<4) ^ (r<<3))]);
  greg16p(v, U, 0); greg16p(v, U, 1); greg16p(v, U, 2); greg16p(v, U, 3); // w11..w8
  v2f z2 = mk2(0.f, 0.f);
  v2f totP=z2, S4P=z2, S5P=z2, S6P=z2, S7P=z2;
  #pragma unroll
  for (int r=0;r<16;r++){
    v2f sq = pk_mul(v[r], v[r]);
    totP = totP + sq;
    if (__popc(r)&1)    S4P = S4P + sq;
    if (__popc(r>>1)&1) S5P = S5P + sq;
    if (__popc(r>>2)&1) S6P = S6P + sq;
    if (__popc(r>>3)&1) S7P = S7P + sq;
  }
  float totA = totP.x + totP.y;
  float S4l = S4P.x + S4P.y, S5l = S5P.x + S5P.y;
  float S6l = S6P.x + S6P.y, S7l = S7P.x + S7P.y;
  float S4h = totA - S4l;
  float S0 = (__popc(tid & 0x1F)&1) ? S4h : S4l;   // parity(ul0..8)
  float S1 = (__popc(tid & 0x1E)&1) ? S4h : S4l;   // parity(ul1..8)
  float S2 = (__popc(tid & 0x1C)&1) ? S4h : S4l;   // parity(ul2..8)
  float S3 = (__popc(tid & 0x18)&1) ? S4h : S4l;   // parity(ul3..8)
  bool u8 = (tid & 16);
  float S4 = u8 ? S4h : S4l;                       // parity(ul4..8)
  float S5 = u8 ? totA - S5l : S5l;
  float S6 = u8 ? totA - S6l : S6l;
  float S7 = u8 ? totA - S7l : S7l;
  float S8 = u8 ? totA : 0.f;
  float K9  = (tid & 32) ? totA : 0.f;
  float K10 = (tid & 64) ? totA : 0.f;
  float K11 = (tid & 128)? totA : 0.f;
  float X45 = xdot16p(v,3), X56 = xdot16p(v,6), X67 = xdot16p(v,12);
  v2f X01P=z2, X12P=z2, X23P=z2, X34P=z2, X78P=z2;
  #pragma unroll
  for (int r=0;r<16;r++){
    float vx = v[r].x, vy = v[r].y;
    X01P = pk_fma(v[r], mk2(swzx<3>(vx),  swzx<3>(vy)),  X01P);   // flips ul0,ul1
    X12P = pk_fma(v[r], mk2(swzx<6>(vx),  swzx<6>(vy)),  X12P);   // flips ul1,ul2
    X23P = pk_fma(v[r], mk2(swzx<12>(vx), swzx<12>(vy)), X23P);   // flips ul2,ul3
    X34P = pk_fma(v[r], mk2(swzx<8>(v[r^1].x), swzx<8>(v[r^1].y)), X34P);   // ul3 x ul4
    X78P = pk_fma(v[r], mk2(swzx<16>(v[r^8].x), swzx<16>(v[r^8].y)), X78P); // ul7 x ul8
  }
  float X01 = X01P.x + X01P.y, X12 = X12P.x + X12P.y, X23 = X23P.x + X23P.y;
  float X34 = X34P.x + X34P.y, X78 = X78P.x + X78P.y;
  float vals[21] = {totA, S0,S1,S2,S3,S4,S5,S6,S7,S8, K9,K10,K11,
                    X01,X12,X23,X34,X45,X56,X67,X78};
  #pragma unroll
  for (int i=0;i<21;i++) vals[i] = wsum(vals[i]);
  if ((tid & 63) == 0){
    float* A = acc + b*ACCS;
    atomicAdd(A+0, vals[0]);
    #pragma unroll
    for (int p=0;p<12;p++) atomicAdd(A+1+p, vals[1+p]);
    if (t&1) atomicAdd(A+13, vals[0]);
    if (t&2) atomicAdd(A+14, vals[0]);
    if (t&4) atomicAdd(A+15, vals[0]);
    float zz = vals[0] - 2.f*vals[1];
    if (t&8) zz = -zz;
    atomicAdd(A+16, zz);
    #pragma unroll
    for (int j=0;j<8;j++) atomicAdd(A+17+j, vals[13+j]);
  }
}

// ---------------- Tail (unchanged, verified) ----------------
__global__ __launch_bounds__(256) void qs_tail(const float* __restrict__ acc, const float* __restrict__ tryv,
    const float* __restrict__ w1, const float* __restrict__ b1,
    const float* __restrict__ w2, const float* __restrict__ b2,
    const float* __restrict__ g1, const float* __restrict__ be1,
    const float* __restrict__ g2, const float* __restrict__ be2,
    const float* __restrict__ wh, const float* __restrict__ bh,
    float* __restrict__ out){
  int b = blockIdx.x * 256 + threadIdx.x;
  if (b >= BSZQ) return;
  const float* A = acc + b*ACCS;
  float tot = A[0];
  float inv = 1.f / tot;
  float Z[16], X[16];
  Z[0] = A[16] * inv;
  Z[1] = 1.f - 2.f*A[15]*inv;
  Z[2] = 1.f - 2.f*A[14]*inv;
  Z[3] = 1.f - 2.f*A[13]*inv;
  #pragma unroll
  for (int w=4; w<15; w++) Z[w] = 1.f - 2.f*A[1 + (15-w)]*inv;
  Z[15] = 1.f - 2.f*A[1]*inv;
  #pragma unroll
  for (int w=0; w<7; w++) X[w] = A[25+w]*inv;
  #pragma unroll
  for (int w=7; w<15; w++) X[w] = A[16 + (15-w)]*inv;
  X[15] = A[32]*inv;
  float th = tryv[1];
  float ct = cosf(th), st = sinf(th);
  float M4[16];
  #pragma unroll
  for (int w=0; w<16; w++) M4[w] = ct*Z[w] - st*X[w];
  float mu = 0.f;
  #pragma unroll
  for (int w=0; w<16; w++) mu += Z[w];
  mu *= (1.f/16.f);
  float var = 0.f;
  #pragma unroll
  for (int w=0; w<16; w++){ float d = Z[w]-mu; var += d*d; }
  var *= (1.f/16.f);
  float rs = rsqrtf(var + 1e-5f);
  float xln[16];
  #pragma unroll
  for (int w=0; w<16; w++) xln[w] = (Z[w]-mu)*rs*g1[16+w] + be1[16+w];
  float h[64];
  for (int j=0;j<64;j++){
    float sacc = b1[64 + j];
    #pragma unroll
    for (int w=0; w<16; w++) sacc += M4[w] * w1[1024 + j*16 + w];
    h[j] = fmaxf(sacc, 0.f);
  }
  float y[16];
  for (int w=0; w<16; w++){
    float sacc = b2[16 + w];
    #pragma unroll
    for (int j=0;j<64;j++) sacc += h[j] * w2[1024 + w*64 + j];
    y[w] = xln[w] + sacc;
  }
  mu = 0.f;
  #pragma unroll
  for (int w=0; w<16; w++) mu += y[w];
  mu *= (1.f/16.f);
  var = 0.f;
  #pragma unroll
  for (int w=0; w<16; w++){ float d = y[w]-mu; var += d*d; }
  var *= (1.f/16.f);
  rs = rsqrtf(var + 1e-5f);
  float o = bh[0];
  #pragma unroll
  for (int w=0; w<16; w++) o += ((y[w]-mu)*rs*g2[16+w] + be2[16+w]) * wh[w];
  out[b] = o;
}

extern "C" void kernel_launch(void* const* d_in, const int* in_sizes, int n_in,
                              void* d_out, int out_size, void* d_ws, size_t ws_size,
                              hipStream_t stream) {
  const float* states = (const float*)d_in[0];
  const float* ra     = (const float*)d_in[1];
  const float* trx    = (const float*)d_in[2];
  const float* tryv   = (const float*)d_in[3];
  const float* w1     = (const float*)d_in[4];
  const float* b1     = (const float*)d_in[5];
  const float* w2     = (const float*)d_in[6];
  const float* b2     = (const float*)d_in[7];
  const float* g1     = (const float*)d_in[8];
  const float* be1    = (const float*)d_in[9];
  const float* g2     = (const float*)d_in[10];
  const float* be2    = (const float*)d_in[11];
  const float* wh     = (const float*)d_in[12];
  const float* bh     = (const float*)d_in[13];
  float* out = (float*)d_out;

  unsigned int* psi = (unsigned int*)d_ws;                                 // 128 MiB (fp16 amps)
  float* acc  = (float*)((char*)d_ws + (size_t)BSZQ*65536*sizeof(float2)); // keep old offset (512 x 40)
  float* gt = out;  // gate table in d_out scratch; qs_tail overwrites it all

  dim3 g(BSZQ*16);
  qs_prep<<<1, 64, 0, stream>>>(ra, trx, tryv, gt);
  qs_p1<<<g, NT, 0, stream>>>(states, gt, psi, acc);
  qs_p2<<<g, NT, 0, stream>>>(psi, gt);
  qs_p4<<<g, NT, 0, stream>>>(psi, gt, acc);
  qs_p5<<<g, NT, 0, stream>>>(psi, gt, acc);
  qs_tail<<<2, 256, 0, stream>>>(acc, tryv, w1, b1, w2, b2, g1, be1, g2, be2, wh, bh, out);
}